// Round 7
// baseline (174.819 us; speedup 1.0000x reference)
//
#include <hip/hip_runtime.h>

#define NC 3000   // num cates
#define NP 3072   // padded (3000/4 = 750 full blocks; blocks 750..767 fully padded)
#define CAP 64    // ELL slots per row
#define HD 64
#define NG 4
#define LQ 50
#define NB 256
#define NQ4 750   // float4 words per adj row = NC/4
#define SBST (NG * HD + 1)   // stride of one Sb partial copy (256 sums + wsum)
#define NBLK 768  // 256 CUs x 3 blocks/CU co-resident (guaranteed by __launch_bounds__(256,3))
#define NREP 96   // release replica lines (8 blocks poll each), 64B-strided

// Write-through (agent-scope) store: value lands at the coherent point (Infinity Cache),
// never a dirty line in a non-coherent XCD L2. Every cross-phase buffer is written ONCE
// and only read in later phases -> no cache can ever hold a stale copy. Readers use
// plain cached loads (L2-speed gathers). Protocol validated R3/R4/R6 (all passed).
__device__ __forceinline__ void stg(float* p, float v) {
  __hip_atomic_store(p, v, __ATOMIC_RELAXED, __HIP_MEMORY_SCOPE_AGENT);
}
__device__ __forceinline__ void stf(unsigned* p, unsigned v) {
  __hip_atomic_store(p, v, __ATOMIC_RELAXED, __HIP_MEMORY_SCOPE_AGENT);
}
__device__ __forceinline__ unsigned ldf(const unsigned* p) {
  return __hip_atomic_load(p, __ATOMIC_RELAXED, __HIP_MEMORY_SCOPE_AGENT);
}

// Zero-RMW tree barrier (phase-valued, one slot array serves all barriers).
//   arrival:  slot[blk] = phase      (768 stores over 48 lines, no serialization)
//   detect:   block 0's 256 threads scan all 768 slots (sole readers, coalesced x3)
//   release:  block 0 stores phase into 96 replica lines; 8 blocks poll each (lane 0 only)
// Monotone phase values make >= checks race-free when fast blocks overwrite their slot
// for barrier i+1 before the root finishes scanning barrier i.
__device__ __forceinline__ void gridbar(unsigned* __restrict__ slot,
                                        unsigned* __restrict__ rep, unsigned phase) {
  __syncthreads();   // each wave drains vmcnt(0) -> block's sc1 data stores are at the IF
  const int tid = threadIdx.x;
  const int blk = blockIdx.x;
  if (blk == 0) {
    if (tid == 0) stf(&slot[0], phase);
    bool d0 = false, d1 = false, d2 = false;
    for (;;) {
      if (!d0) d0 = (ldf(&slot[tid]) >= phase);
      if (!d1) d1 = (ldf(&slot[tid + 256]) >= phase);
      if (!d2) d2 = (ldf(&slot[tid + 512]) >= phase);
      if (__syncthreads_and(d0 && d1 && d2)) break;
      __builtin_amdgcn_s_sleep(1);
    }
    if (tid < NREP) stf(&rep[tid * 16], phase);
  } else {
    if (tid == 0) {
      stf(&slot[blk], phase);
      while (ldf(&rep[(blk % NREP) * 16]) < phase) __builtin_amdgcn_s_sleep(1);
    }
    __syncthreads();
  }
  asm volatile("" ::: "memory");
}

// Issue-then-accumulate gather (replaces the serial 8-at-a-time chain). All ~d scattered
// loads are issued up front into a fully-unrolled register array (static indices only),
// then a single wait covers the whole accumulate pass: ONE memory-latency round instead
// of ceil(d/8) serialized rounds. Collapses both phase time and cross-row degree skew.
// Guards are wave-uniform (d is wave-uniform); g_[e] is read under the same guard it was
// written under. Slots >= d hold (vreg=0, creg=0) -> exact-zero terms.
#define GATHER_ALL(acc, vreg, creg, zin, d)                                        \
  {                                                                                \
    const int dro_ = ((d) + 7) & ~7;                                               \
    float g_[64];                                                                  \
    _Pragma("unroll")                                                              \
    for (int e = 0; e < 64; e += 8) {                                              \
      if (e < dro_) {                                                              \
        int c0 = __shfl(creg, e + 0), c1 = __shfl(creg, e + 1);                    \
        int c2 = __shfl(creg, e + 2), c3 = __shfl(creg, e + 3);                    \
        int c4 = __shfl(creg, e + 4), c5 = __shfl(creg, e + 5);                    \
        int c6 = __shfl(creg, e + 6), c7 = __shfl(creg, e + 7);                    \
        g_[e + 0] = zin[c0 * HD + lane]; g_[e + 1] = zin[c1 * HD + lane];          \
        g_[e + 2] = zin[c2 * HD + lane]; g_[e + 3] = zin[c3 * HD + lane];          \
        g_[e + 4] = zin[c4 * HD + lane]; g_[e + 5] = zin[c5 * HD + lane];          \
        g_[e + 6] = zin[c6 * HD + lane]; g_[e + 7] = zin[c7 * HD + lane];          \
      }                                                                            \
    }                                                                              \
    _Pragma("unroll")                                                              \
    for (int e = 0; e < 64; e += 8) {                                              \
      if (e < dro_) {                                                              \
        acc += __shfl(vreg, e + 0) * g_[e + 0] + __shfl(vreg, e + 1) * g_[e + 1]   \
             + __shfl(vreg, e + 2) * g_[e + 2] + __shfl(vreg, e + 3) * g_[e + 3];  \
        acc += __shfl(vreg, e + 4) * g_[e + 4] + __shfl(vreg, e + 5) * g_[e + 5]   \
             + __shfl(vreg, e + 6) * g_[e + 6] + __shfl(vreg, e + 7) * g_[e + 7];  \
      }                                                                            \
    }                                                                              \
  }

// one hop: z_out = 0.85 * (A z_in)[row] + 0.15 * v[row]   (per-lane feature)
__device__ __forceinline__ float hopz(const float* __restrict__ zin, float vreg, int creg,
                                      int d, int lane, float vown) {
  float acc = 0.f;
  GATHER_ALL(acc, vreg, creg, zin, d);
  return 0.85f * acc + 0.15f * vown;
}

// q/k/v projections for one row held per-lane (lane = output col, h row broadcast via shfl)
__device__ __forceinline__ void qkv3(float h, const float* __restrict__ Wq,
                                     const float* __restrict__ Wk, const float* __restrict__ Wv,
                                     int lane, float& aq, float& ak, float& av) {
  aq = 0.f; ak = 0.f; av = 0.f;
#pragma unroll 16
  for (int f = 0; f < HD; ++f) {
    float hv = __shfl(h, f);
    aq += hv * Wq[f * HD + lane];
    ak += hv * Wk[f * HD + lane];
    av += hv * Wv[f * HD + lane];
  }
}

// edge scores + row softmax + hop1: returns normalized A-row value for this lane's slot
__device__ __forceinline__ float score_hop(const float* __restrict__ kbuf,
                                           const float* __restrict__ vsrc, float qreg, int creg,
                                           int d, int lane, float vown,
                                           float* __restrict__ zout, int row) {
  float acc = 0.f;
  const float4* kr = reinterpret_cast<const float4*>(kbuf + creg * HD);
#pragma unroll
  for (int i = 0; i < 16; ++i) {
    float4 k4 = kr[i];
    acc += __shfl(qreg, 4 * i + 0) * k4.x;
    acc += __shfl(qreg, 4 * i + 1) * k4.y;
    acc += __shfl(qreg, 4 * i + 2) * k4.z;
    acc += __shfl(qreg, 4 * i + 3) * k4.w;
  }
  float e = (lane < d) ? __expf(acc * 0.125f) : 0.f;  // |s| O(1): no max-sub needed in fp32
  float s = e;
#pragma unroll
  for (int off = 1; off < 64; off <<= 1) s += __shfl_xor(s, off);
  float vreg = (s > 0.f) ? e / s : 0.f;               // 0 for lane >= d
  float hacc = 0.f;
  GATHER_ALL(hacc, vreg, creg, vsrc, d);
  stg(zout + row * HD + lane, 0.85f * hacc + 0.15f * vown);
  return vreg;
}

// ---- init: zero slots/replicas + Sb partials (workspace is re-poisoned between runs).
__global__ __launch_bounds__(1024) void k_init(unsigned* __restrict__ slot,
                                               unsigned* __restrict__ rep,
                                               float* __restrict__ Sbp) {
  const int t = threadIdx.x;
  if (t < NBLK) stf(&slot[t], 0u);
  for (int i = t; i < NREP * 16; i += 1024) stf(&rep[i], 0u);
  for (int i = t; i < 4 * SBST; i += 1024)
    __hip_atomic_store(&Sbp[i], 0.f, __ATOMIC_RELAXED, __HIP_MEMORY_SCOPE_AGENT);
}

// ---- single mega-kernel: 9 zero-RMW tree barriers. 768 blocks x 256 thr = 3 blocks/CU
// co-resident. Row state (ELL cols, degree, A-row, q, v, layer-1 h) stays in registers;
// cross-phase data goes through write-once write-through buffers.
__global__ __launch_bounds__(256, 3) void k_mega(
    const int* __restrict__ cate, const float* __restrict__ adj, const float* __restrict__ emb,
    const float* __restrict__ Wq, const float* __restrict__ Wk, const float* __restrict__ Wv,
    const float* __restrict__ Wg, const float* __restrict__ bg, const float* __restrict__ Wp,
    const float* __restrict__ bp, const float* __restrict__ gamma, const float* __restrict__ beta,
    float* __restrict__ out, float* __restrict__ kf, float* __restrict__ vf,
    float* __restrict__ kf2, float* __restrict__ vf2,
    float* __restrict__ z1, float* __restrict__ z2, float* __restrict__ z3,
    float* __restrict__ z5, float* __restrict__ z6, float* __restrict__ z7,
    float* __restrict__ hf, float* __restrict__ s2, float* __restrict__ Sbp,
    unsigned* __restrict__ slot, unsigned* __restrict__ rep) {
  const int tid = threadIdx.x, lane = tid & 63, wave = tid >> 6;
  const int blk = blockIdx.x;
  const int row = blk * 4 + wave;
  const bool inC = (row < NC);

  __shared__ int slds[4][CAP];     // P0 ELL slot scatter (same-wave access only)
  __shared__ float Sl[NG * HD];    // P8 block partial
  __shared__ float Wl[4];
  __shared__ int cs[LQ];           // P9
  __shared__ float red[8][HD];

  // ---------------- P0: adj pack + qkv layer 1 ----------------
  slds[wave][lane] = 0;            // zero-fill tail slots (vreg tail is 0 too)
  int d = 0;
  if (inC) {
    const float4* arow = reinterpret_cast<const float4*>(adj + (size_t)row * NC);
    const unsigned long long mlane = (1ull << lane) - 1ull;
    int base = 0;  // wave-uniform running edge count
#pragma unroll 3
    for (int g = 0; g < 12; ++g) {
      int idx = g * 64 + lane;
      float4 a4 = (idx < NQ4) ? arow[idx] : make_float4(0.f, 0.f, 0.f, 0.f);
      unsigned long long b0 = __ballot(a4.x != 0.f);
      unsigned long long b1 = __ballot(a4.y != 0.f);
      unsigned long long b2 = __ballot(a4.z != 0.f);
      unsigned long long b3 = __ballot(a4.w != 0.f);
      if (a4.x != 0.f) { int s = base + __popcll(b0 & mlane); if (s < CAP) slds[wave][s] = 4 * idx + 0; }
      base += __popcll(b0);
      if (a4.y != 0.f) { int s = base + __popcll(b1 & mlane); if (s < CAP) slds[wave][s] = 4 * idx + 1; }
      base += __popcll(b1);
      if (a4.z != 0.f) { int s = base + __popcll(b2 & mlane); if (s < CAP) slds[wave][s] = 4 * idx + 2; }
      base += __popcll(b2);
      if (a4.w != 0.f) { int s = base + __popcll(b3 & mlane); if (s < CAP) slds[wave][s] = 4 * idx + 3; }
      base += __popcll(b3);
    }
    d = (base < CAP) ? base : CAP;
  }
  const int creg = slds[wave][lane];   // same-wave LDS readback; no block barrier needed
  float qreg = 0.f, vown = 0.f;
  if (inC) {
    float hreg = emb[row * HD + lane];
    float aq, ak, av;
    qkv3(hreg, Wq, Wk, Wv, lane, aq, ak, av);
    stg(kf + row * HD + lane, ak);   // gathered by others -> write-through
    stg(vf + row * HD + lane, av);
    qreg = aq;                       // own-row only -> register
    vown = av;
  }
  gridbar(slot, rep, 1);

  // ---------------- P1: layer-1 scores + softmax + hop1 ----------------
  float vreg = 0.f;
  if (inC) vreg = score_hop(kf, vf, qreg, creg, d, lane, vown, z1, row);
  gridbar(slot, rep, 2);
  // ---------------- P2/P3: hops 2,3 ----------------
  if (inC) stg(z2 + row * HD + lane, hopz(z1, vreg, creg, d, lane, vown));
  gridbar(slot, rep, 3);
  if (inC) stg(z3 + row * HD + lane, hopz(z2, vreg, creg, d, lane, vown));
  gridbar(slot, rep, 4);
  // ---------------- P4: hop4 + residual + qkv layer 2 ----------------
  float h1 = 0.f;
  if (inC) {
    float z = hopz(z3, vreg, creg, d, lane, vown);
    h1 = emb[row * HD + lane] + z;    // layer-1 output stays in register until P8
    float aq, ak, av;
    qkv3(h1, Wq + HD * HD, Wk + HD * HD, Wv + HD * HD, lane, aq, ak, av);
    stg(kf2 + row * HD + lane, ak);
    stg(vf2 + row * HD + lane, av);
    qreg = aq; vown = av;
  }
  gridbar(slot, rep, 5);
  // ---------------- P5: layer-2 scores + softmax + hop1 ----------------
  if (inC) vreg = score_hop(kf2, vf2, qreg, creg, d, lane, vown, z5, row);
  gridbar(slot, rep, 6);
  // ---------------- P6/P7: hops 2,3 ----------------
  if (inC) stg(z6 + row * HD + lane, hopz(z5, vreg, creg, d, lane, vown));
  gridbar(slot, rep, 7);
  if (inC) stg(z7 + row * HD + lane, hopz(z6, vreg, creg, d, lane, vown));
  gridbar(slot, rep, 8);
  // ---------------- P8: hop4 + residual + cluster softmax + Sb/wsum partials ----------------
  if (tid < NG * HD) Sl[tid] = 0.f;
  if (tid < 4) Wl[tid] = 0.f;
  __syncthreads();
  if (inC) {
    float z = hopz(z7, vreg, creg, d, lane, vown);
    float h = h1 + z;
    stg(hf + row * HD + lane, h);
    float4 wg = *reinterpret_cast<const float4*>(Wg + lane * NG);
    float a0 = h * wg.x, a1 = h * wg.y, a2 = h * wg.z, a3 = h * wg.w;
#pragma unroll
    for (int off = 1; off < 64; off <<= 1) {
      a0 += __shfl_xor(a0, off); a1 += __shfl_xor(a1, off);
      a2 += __shfl_xor(a2, off); a3 += __shfl_xor(a3, off);
    }
    float lg0 = a0 + bg[0], lg1 = a1 + bg[1], lg2 = a2 + bg[2], lg3 = a3 + bg[3];
    float mx = fmaxf(fmaxf(lg0, lg1), fmaxf(lg2, lg3));
    float e0 = __expf(lg0 - mx), e1 = __expf(lg1 - mx), e2 = __expf(lg2 - mx), e3 = __expf(lg3 - mx);
    float inv = 1.f / (e0 + e1 + e2 + e3);
    float p0 = e0 * inv, p1 = e1 * inv, p2 = e2 * inv, p3 = e3 * inv;
    if (lane == 0) stg(s2 + row, p0 * p0 + p1 * p1 + p2 * p2 + p3 * p3);
    float w = Wp[row];
    atomicAdd(&Sl[0 * HD + lane], p0 * w * h);
    atomicAdd(&Sl[1 * HD + lane], p1 * w * h);
    atomicAdd(&Sl[2 * HD + lane], p2 * w * h);
    atomicAdd(&Sl[3 * HD + lane], p3 * w * h);
    if (lane == 0) Wl[wave] = w;
  }
  __syncthreads();
  if (blk * 4 < NC) {   // blocks 750..767 are fully padded: skip
    float* Sc = Sbp + (blk & 3) * SBST;   // 4 copies: device-scope RMWs at the coherent point
    if (tid < NG * HD) atomicAdd(&Sc[tid], Sl[tid]);
    if (tid == 0) atomicAdd(&Sc[NG * HD], Wl[0] + Wl[1] + Wl[2] + Wl[3]);
  }
  gridbar(slot, rep, 9);
  // ---------------- P9: per-user closed-form BN + pool (blocks 0..NB-1) ----------------
  if (blk < NB) {
    if (tid < LQ) cs[tid] = cate[blk * LQ + tid];
    __syncthreads();
    float msum = 0.f, qsum = 0.f;
#pragma unroll 4
    for (int l = wave; l < LQ; l += 4) {
      int c = cs[l];
      if (c != 0) {
        float gv = hf[c * HD + lane];
        msum += gv;
        qsum += s2[c] * gv * gv;
      }
    }
    red[wave][lane] = msum;
    red[4 + wave][lane] = qsum;
    __syncthreads();
    if (wave == 0) {
      msum = red[0][lane] + red[1][lane] + red[2][lane] + red[3][lane];
      qsum = red[4][lane] + red[5][lane] + red[6][lane] + red[7][lane];
      const float cntf = 1.f / (NG * LQ);
      float mean = msum * cntf;
      float var = fmaxf(qsum * cntf - mean * mean, 0.f);
      float invs = rsqrtf(var + 1e-5f);
      float gam = gamma[lane], bet = beta[lane], bpv = bp[0];
      float wsum = Sbp[NG * HD] + Sbp[SBST + NG * HD] + Sbp[2 * SBST + NG * HD] + Sbp[3 * SBST + NG * HD];
#pragma unroll
      for (int g = 0; g < NG; ++g) {
        float sg = Sbp[0 * SBST + g * HD + lane] + Sbp[1 * SBST + g * HD + lane] +
                   Sbp[2 * SBST + g * HD + lane] + Sbp[3 * SBST + g * HD + lane];
        out[blk * (NG * HD) + g * HD + lane] = invs * gam * (sg - mean * wsum) + bet * wsum + bpv;
      }
    }
  }
}

extern "C" void kernel_launch(void* const* d_in, const int* in_sizes, int n_in,
                              void* d_out, int out_size, void* d_ws, size_t ws_size,
                              hipStream_t stream) {
  const int* cate = (const int*)d_in[0];
  const float* adj = (const float*)d_in[1];
  const float* emb = (const float*)d_in[2];
  const float* Wq = (const float*)d_in[3];
  const float* Wk = (const float*)d_in[4];
  const float* Wv = (const float*)d_in[5];
  const float* Wg = (const float*)d_in[6];
  const float* bg = (const float*)d_in[7];
  const float* Wp = (const float*)d_in[8];
  const float* bp = (const float*)d_in[9];
  const float* gamma = (const float*)d_in[10];
  const float* beta = (const float*)d_in[11];
  float* out = (float*)d_out;

  char* p = (char*)d_ws;
  auto carve = [&](size_t bytes) { char* r = p; p += (bytes + 255) & ~(size_t)255; return r; };
  float* kf = (float*)carve((size_t)NP * HD * 4);
  float* vf = (float*)carve((size_t)NP * HD * 4);
  float* kf2 = (float*)carve((size_t)NP * HD * 4);
  float* vf2 = (float*)carve((size_t)NP * HD * 4);
  float* z1 = (float*)carve((size_t)NP * HD * 4);
  float* z2 = (float*)carve((size_t)NP * HD * 4);
  float* z3 = (float*)carve((size_t)NP * HD * 4);
  float* z5 = (float*)carve((size_t)NP * HD * 4);
  float* z6 = (float*)carve((size_t)NP * HD * 4);
  float* z7 = (float*)carve((size_t)NP * HD * 4);
  float* hf = (float*)carve((size_t)NP * HD * 4);
  float* s2 = (float*)carve((size_t)NP * 4);
  float* Sbp = (float*)carve((size_t)4 * SBST * 4);
  unsigned* slot = (unsigned*)carve((size_t)NBLK * 4);
  unsigned* rep = (unsigned*)carve((size_t)NREP * 16 * 4);

  k_init<<<1, 1024, 0, stream>>>(slot, rep, Sbp);
  k_mega<<<NBLK, 256, 0, stream>>>(cate, adj, emb, Wq, Wk, Wv, Wg, bg, Wp, bp, gamma, beta,
                                   out, kf, vf, kf2, vf2, z1, z2, z3, z5, z6, z7,
                                   hf, s2, Sbp, slot, rep);
}

// Round 8
// 156.719 us; speedup vs baseline: 1.1155x; 1.1155x over previous
//
#include <hip/hip_runtime.h>

#define NC 3000   // num cates
#define NP 3072   // padded
#define CAP 64    // ELL slots per row
#define HD 64
#define NG 4
#define LQ 50
#define NB 256
#define NQ4 750   // float4 words per adj row = NC/4
#define SBST (NG * HD + 1)   // stride of one Sb partial copy (256 sums + wsum)
#define NSBC 8    // Sb partial copies (contention ~31 blocks/address)
#define NBLK 256  // 256 blocks x 768 thr = 1 block/CU, 12 waves/CU (same work layout as before)
#define TPB 768
#define WPB 12    // waves (rows) per block
#define NREP 32   // release replica lines (~8 blocks poll each), 64B-strided

// Write-through (agent-scope) store: value lands at the coherent point (Infinity Cache),
// never a dirty line in a non-coherent XCD L2. Every cross-phase buffer is written ONCE
// and only read in later phases -> no cache can ever hold a stale copy. Readers use
// plain cached loads (L2-speed gathers). Protocol validated R3/R4/R6/R7 (all passed).
__device__ __forceinline__ void stg(float* p, float v) {
  __hip_atomic_store(p, v, __ATOMIC_RELAXED, __HIP_MEMORY_SCOPE_AGENT);
}
__device__ __forceinline__ void stf(unsigned* p, unsigned v) {
  __hip_atomic_store(p, v, __ATOMIC_RELAXED, __HIP_MEMORY_SCOPE_AGENT);
}
__device__ __forceinline__ unsigned ldf(const unsigned* p) {
  return __hip_atomic_load(p, __ATOMIC_RELAXED, __HIP_MEMORY_SCOPE_AGENT);
}

// Zero-RMW tree barrier, 256 participants (was 768 -- R6/R7 showed arrival mechanics and
// work restructure are not the residual; participant-scaled traffic/wake-up is the
// remaining candidate). arrival: slot[blk]=phase (256 stores / 16 lines). detect: block
// 0, one load per thread (tid<256). release: 32 replicas, ~8 pollers each (lane 0 only).
__device__ __forceinline__ void gridbar(unsigned* __restrict__ slot,
                                        unsigned* __restrict__ rep, unsigned phase) {
  __syncthreads();   // drains vmcnt(0) -> block's sc1 data stores are at the IF
  const int tid = threadIdx.x;
  const int blk = blockIdx.x;
  if (blk == 0) {
    if (tid == 0) stf(&slot[0], phase);
    bool dn = (tid >= NBLK);
    for (;;) {
      if (!dn) dn = (ldf(&slot[tid]) >= phase);
      if (__syncthreads_and(dn)) break;
      __builtin_amdgcn_s_sleep(1);
    }
    if (tid < NREP) stf(&rep[tid * 16], phase);
  } else {
    if (tid == 0) {
      stf(&slot[blk], phase);
      while (ldf(&rep[(blk & (NREP - 1)) * 16]) < phase) __builtin_amdgcn_s_sleep(1);
    }
    __syncthreads();
  }
  asm volatile("" ::: "memory");
}

// one hop: z_out = 0.85 * (A z_in)[row] + 0.15 * v[row]. A-row lives in LDS as packed
// int2{col, val}: one broadcast ds_read_b64 per edge replaces two ds_bpermute shfls.
// Slots >= d hold {0, 0} -> exact-zero terms. d is wave-uniform.
__device__ __forceinline__ float hopz(const float* __restrict__ zin, const int2* scvw,
                                      int d, int lane, float vown) {
  float acc = 0.f;
  const int dro = (d + 7) & ~7;
  for (int e = 0; e < dro; e += 8) {
    int2 a0 = scvw[e + 0], a1 = scvw[e + 1], a2 = scvw[e + 2], a3 = scvw[e + 3];
    int2 a4 = scvw[e + 4], a5 = scvw[e + 5], a6 = scvw[e + 6], a7 = scvw[e + 7];
    float z0 = zin[a0.x * HD + lane], z1 = zin[a1.x * HD + lane];
    float z2 = zin[a2.x * HD + lane], z3 = zin[a3.x * HD + lane];
    float z4 = zin[a4.x * HD + lane], z5 = zin[a5.x * HD + lane];
    float z6 = zin[a6.x * HD + lane], z7 = zin[a7.x * HD + lane];
    acc += __int_as_float(a0.y) * z0 + __int_as_float(a1.y) * z1
         + __int_as_float(a2.y) * z2 + __int_as_float(a3.y) * z3;
    acc += __int_as_float(a4.y) * z4 + __int_as_float(a5.y) * z5
         + __int_as_float(a6.y) * z6 + __int_as_float(a7.y) * z7;
  }
  return 0.85f * acc + 0.15f * vown;
}

// q/k/v projections for one row held per-lane (lane = output col, h row broadcast via shfl)
__device__ __forceinline__ void qkv3(float h, const float* __restrict__ Wq,
                                     const float* __restrict__ Wk, const float* __restrict__ Wv,
                                     int lane, float& aq, float& ak, float& av) {
  aq = 0.f; ak = 0.f; av = 0.f;
#pragma unroll 16
  for (int f = 0; f < HD; ++f) {
    float hv = __shfl(h, f);
    aq += hv * Wq[f * HD + lane];
    ak += hv * Wk[f * HD + lane];
    av += hv * Wv[f * HD + lane];
  }
}

// edge scores + row softmax + hop1. Writes the normalized A-row into scvw (packed with
// cols) for this layer's hops; same-wave LDS write->read ordering handled by compiler.
__device__ __forceinline__ void score_hop(const float* __restrict__ kbuf,
                                          const float* __restrict__ vsrc, float qreg, int creg,
                                          int d, int lane, float vown,
                                          float* __restrict__ zout, int row, int2* scvw) {
  float acc = 0.f;
  const float4* kr = reinterpret_cast<const float4*>(kbuf + creg * HD);
#pragma unroll
  for (int i = 0; i < 16; ++i) {
    float4 k4 = kr[i];
    acc += __shfl(qreg, 4 * i + 0) * k4.x;
    acc += __shfl(qreg, 4 * i + 1) * k4.y;
    acc += __shfl(qreg, 4 * i + 2) * k4.z;
    acc += __shfl(qreg, 4 * i + 3) * k4.w;
  }
  float e = (lane < d) ? __expf(acc * 0.125f) : 0.f;  // |s| O(1): no max-sub needed in fp32
  float s = e;
#pragma unroll
  for (int off = 1; off < 64; off <<= 1) s += __shfl_xor(s, off);
  float vreg = (s > 0.f) ? e / s : 0.f;               // 0 for lane >= d (creg tail = 0)
  scvw[lane] = make_int2(creg, __float_as_int(vreg));
  float hacc = hopz(vsrc, scvw, d, lane, vown);
  stg(zout + row * HD + lane, hacc);
}

// ---- init: zero slots/replicas + Sb partials (workspace is re-poisoned between runs).
__global__ __launch_bounds__(1024) void k_init(unsigned* __restrict__ slot,
                                               unsigned* __restrict__ rep,
                                               float* __restrict__ Sbp) {
  const int t = threadIdx.x;
  if (t < NBLK) stf(&slot[t], 0u);
  for (int i = t; i < NREP * 16; i += 1024) stf(&rep[i], 0u);
  for (int i = t; i < NSBC * SBST; i += 1024)
    __hip_atomic_store(&Sbp[i], 0.f, __ATOMIC_RELAXED, __HIP_MEMORY_SCOPE_AGENT);
}

// ---- single mega-kernel: 9 tree barriers, 256-participant. 256 blocks x 768 thr =
// 1 block/CU, 12 waves/CU (same per-CU work as the 768-block layout). Row state stays
// in registers; A-row (col,val) in LDS; cross-phase data through write-once buffers.
__global__ __launch_bounds__(TPB, 1) void k_mega(
    const int* __restrict__ cate, const float* __restrict__ adj, const float* __restrict__ emb,
    const float* __restrict__ Wq, const float* __restrict__ Wk, const float* __restrict__ Wv,
    const float* __restrict__ Wg, const float* __restrict__ bg, const float* __restrict__ Wp,
    const float* __restrict__ bp, const float* __restrict__ gamma, const float* __restrict__ beta,
    float* __restrict__ out, float* __restrict__ kf, float* __restrict__ vf,
    float* __restrict__ kf2, float* __restrict__ vf2,
    float* __restrict__ z1, float* __restrict__ z2, float* __restrict__ z3,
    float* __restrict__ z5, float* __restrict__ z6, float* __restrict__ z7,
    float* __restrict__ hf, float* __restrict__ s2, float* __restrict__ Sbp,
    unsigned* __restrict__ slot, unsigned* __restrict__ rep) {
  const int tid = threadIdx.x, lane = tid & 63, wave = tid >> 6;
  const int blk = blockIdx.x;
  const int row = blk * WPB + wave;
  const bool inC = (row < NC);

  __shared__ int2 scv[WPB][CAP];   // packed (col, A-val) per slot; per-wave rows only
  __shared__ float Sl[NG * HD];    // P8 block partial
  __shared__ float Wl[WPB];
  __shared__ int cs[LQ];           // P9
  __shared__ float red[2 * WPB][HD];

  // ---------------- P0: adj pack + qkv layer 1 ----------------
  scv[wave][lane] = make_int2(0, 0);   // tail slots: col 0, val 0 (exact-zero terms)
  int d = 0;
  if (inC) {
    const float4* arow = reinterpret_cast<const float4*>(adj + (size_t)row * NC);
    const unsigned long long mlane = (1ull << lane) - 1ull;
    int base = 0;  // wave-uniform running edge count
#pragma unroll 3
    for (int g = 0; g < 12; ++g) {
      int idx = g * 64 + lane;
      float4 a4 = (idx < NQ4) ? arow[idx] : make_float4(0.f, 0.f, 0.f, 0.f);
      unsigned long long b0 = __ballot(a4.x != 0.f);
      unsigned long long b1 = __ballot(a4.y != 0.f);
      unsigned long long b2 = __ballot(a4.z != 0.f);
      unsigned long long b3 = __ballot(a4.w != 0.f);
      if (a4.x != 0.f) { int s = base + __popcll(b0 & mlane); if (s < CAP) scv[wave][s].x = 4 * idx + 0; }
      base += __popcll(b0);
      if (a4.y != 0.f) { int s = base + __popcll(b1 & mlane); if (s < CAP) scv[wave][s].x = 4 * idx + 1; }
      base += __popcll(b1);
      if (a4.z != 0.f) { int s = base + __popcll(b2 & mlane); if (s < CAP) scv[wave][s].x = 4 * idx + 2; }
      base += __popcll(b2);
      if (a4.w != 0.f) { int s = base + __popcll(b3 & mlane); if (s < CAP) scv[wave][s].x = 4 * idx + 3; }
      base += __popcll(b3);
    }
    d = (base < CAP) ? base : CAP;
  }
  const int creg = scv[wave][lane].x;  // same-wave LDS readback; no block barrier needed
  int2* scvw = &scv[wave][0];
  float qreg = 0.f, vown = 0.f;
  if (inC) {
    float hreg = emb[row * HD + lane];
    float aq, ak, av;
    qkv3(hreg, Wq, Wk, Wv, lane, aq, ak, av);
    stg(kf + row * HD + lane, ak);   // gathered by others -> write-through
    stg(vf + row * HD + lane, av);
    qreg = aq;                       // own-row only -> register
    vown = av;
  }
  gridbar(slot, rep, 1);

  // ---------------- P1: layer-1 scores + softmax + hop1 ----------------
  if (inC) score_hop(kf, vf, qreg, creg, d, lane, vown, z1, row, scvw);
  gridbar(slot, rep, 2);
  // ---------------- P2/P3: hops 2,3 ----------------
  if (inC) stg(z2 + row * HD + lane, hopz(z1, scvw, d, lane, vown));
  gridbar(slot, rep, 3);
  if (inC) stg(z3 + row * HD + lane, hopz(z2, scvw, d, lane, vown));
  gridbar(slot, rep, 4);
  // ---------------- P4: hop4 + residual + qkv layer 2 ----------------
  float h1 = 0.f;
  if (inC) {
    float z = hopz(z3, scvw, d, lane, vown);
    h1 = emb[row * HD + lane] + z;    // layer-1 output stays in register until P8
    float aq, ak, av;
    qkv3(h1, Wq + HD * HD, Wk + HD * HD, Wv + HD * HD, lane, aq, ak, av);
    stg(kf2 + row * HD + lane, ak);
    stg(vf2 + row * HD + lane, av);
    qreg = aq; vown = av;
  }
  gridbar(slot, rep, 5);
  // ---------------- P5: layer-2 scores + softmax + hop1 ----------------
  if (inC) score_hop(kf2, vf2, qreg, creg, d, lane, vown, z5, row, scvw);
  gridbar(slot, rep, 6);
  // ---------------- P6/P7: hops 2,3 ----------------
  if (inC) stg(z6 + row * HD + lane, hopz(z5, scvw, d, lane, vown));
  gridbar(slot, rep, 7);
  if (inC) stg(z7 + row * HD + lane, hopz(z6, scvw, d, lane, vown));
  gridbar(slot, rep, 8);
  // ---------------- P8: hop4 + residual + cluster softmax + Sb/wsum partials ----------------
  if (tid < NG * HD) Sl[tid] = 0.f;
  if (tid < WPB) Wl[tid] = 0.f;
  __syncthreads();
  if (inC) {
    float z = hopz(z7, scvw, d, lane, vown);
    float h = h1 + z;
    stg(hf + row * HD + lane, h);
    float4 wg = *reinterpret_cast<const float4*>(Wg + lane * NG);
    float a0 = h * wg.x, a1 = h * wg.y, a2 = h * wg.z, a3 = h * wg.w;
#pragma unroll
    for (int off = 1; off < 64; off <<= 1) {
      a0 += __shfl_xor(a0, off); a1 += __shfl_xor(a1, off);
      a2 += __shfl_xor(a2, off); a3 += __shfl_xor(a3, off);
    }
    float lg0 = a0 + bg[0], lg1 = a1 + bg[1], lg2 = a2 + bg[2], lg3 = a3 + bg[3];
    float mx = fmaxf(fmaxf(lg0, lg1), fmaxf(lg2, lg3));
    float e0 = __expf(lg0 - mx), e1 = __expf(lg1 - mx), e2 = __expf(lg2 - mx), e3 = __expf(lg3 - mx);
    float inv = 1.f / (e0 + e1 + e2 + e3);
    float p0 = e0 * inv, p1 = e1 * inv, p2 = e2 * inv, p3 = e3 * inv;
    if (lane == 0) stg(s2 + row, p0 * p0 + p1 * p1 + p2 * p2 + p3 * p3);
    float w = Wp[row];
    atomicAdd(&Sl[0 * HD + lane], p0 * w * h);
    atomicAdd(&Sl[1 * HD + lane], p1 * w * h);
    atomicAdd(&Sl[2 * HD + lane], p2 * w * h);
    atomicAdd(&Sl[3 * HD + lane], p3 * w * h);
    if (lane == 0) Wl[wave] = w;
  }
  __syncthreads();
  if (blk * WPB < NC) {   // blocks 250..255 are fully padded: skip
    float* Sc = Sbp + (blk & (NSBC - 1)) * SBST;  // 8 copies: ~31 blocks/address at the IF
    if (tid < NG * HD) atomicAdd(&Sc[tid], Sl[tid]);
    if (tid == 0) {
      float ws = 0.f;
#pragma unroll
      for (int i = 0; i < WPB; ++i) ws += Wl[i];
      atomicAdd(&Sc[NG * HD], ws);
    }
  }
  gridbar(slot, rep, 9);
  // ---------------- P9: per-user closed-form BN + pool (one user per block) ----------------
  if (blk < NB) {
    if (tid < LQ) cs[tid] = cate[blk * LQ + tid];
    __syncthreads();
    float msum = 0.f, qsum = 0.f;
    for (int l = wave; l < LQ; l += WPB) {
      int c = cs[l];
      if (c != 0) {
        float gv = hf[c * HD + lane];
        msum += gv;
        qsum += s2[c] * gv * gv;
      }
    }
    red[wave][lane] = msum;
    red[WPB + wave][lane] = qsum;
    __syncthreads();
    if (wave == 0) {
      msum = 0.f; qsum = 0.f;
#pragma unroll
      for (int i = 0; i < WPB; ++i) { msum += red[i][lane]; qsum += red[WPB + i][lane]; }
      const float cntf = 1.f / (NG * LQ);
      float mean = msum * cntf;
      float var = fmaxf(qsum * cntf - mean * mean, 0.f);
      float invs = rsqrtf(var + 1e-5f);
      float gam = gamma[lane], bet = beta[lane], bpv = bp[0];
      float wsum = 0.f;
#pragma unroll
      for (int i = 0; i < NSBC; ++i) wsum += Sbp[i * SBST + NG * HD];
#pragma unroll
      for (int g = 0; g < NG; ++g) {
        float sg = 0.f;
#pragma unroll
        for (int i = 0; i < NSBC; ++i) sg += Sbp[i * SBST + g * HD + lane];
        out[blk * (NG * HD) + g * HD + lane] = invs * gam * (sg - mean * wsum) + bet * wsum + bpv;
      }
    }
  }
}

extern "C" void kernel_launch(void* const* d_in, const int* in_sizes, int n_in,
                              void* d_out, int out_size, void* d_ws, size_t ws_size,
                              hipStream_t stream) {
  const int* cate = (const int*)d_in[0];
  const float* adj = (const float*)d_in[1];
  const float* emb = (const float*)d_in[2];
  const float* Wq = (const float*)d_in[3];
  const float* Wk = (const float*)d_in[4];
  const float* Wv = (const float*)d_in[5];
  const float* Wg = (const float*)d_in[6];
  const float* bg = (const float*)d_in[7];
  const float* Wp = (const float*)d_in[8];
  const float* bp = (const float*)d_in[9];
  const float* gamma = (const float*)d_in[10];
  const float* beta = (const float*)d_in[11];
  float* out = (float*)d_out;

  char* p = (char*)d_ws;
  auto carve = [&](size_t bytes) { char* r = p; p += (bytes + 255) & ~(size_t)255; return r; };
  float* kf = (float*)carve((size_t)NP * HD * 4);
  float* vf = (float*)carve((size_t)NP * HD * 4);
  float* kf2 = (float*)carve((size_t)NP * HD * 4);
  float* vf2 = (float*)carve((size_t)NP * HD * 4);
  float* z1 = (float*)carve((size_t)NP * HD * 4);
  float* z2 = (float*)carve((size_t)NP * HD * 4);
  float* z3 = (float*)carve((size_t)NP * HD * 4);
  float* z5 = (float*)carve((size_t)NP * HD * 4);
  float* z6 = (float*)carve((size_t)NP * HD * 4);
  float* z7 = (float*)carve((size_t)NP * HD * 4);
  float* hf = (float*)carve((size_t)NP * HD * 4);
  float* s2 = (float*)carve((size_t)NP * 4);
  float* Sbp = (float*)carve((size_t)NSBC * SBST * 4);
  unsigned* slot = (unsigned*)carve((size_t)NBLK * 4);
  unsigned* rep = (unsigned*)carve((size_t)NREP * 16 * 4);

  k_init<<<1, 1024, 0, stream>>>(slot, rep, Sbp);
  k_mega<<<NBLK, TPB, 0, stream>>>(cate, adj, emb, Wq, Wk, Wv, Wg, bg, Wp, bp, gamma, beta,
                                   out, kf, vf, kf2, vf2, z1, z2, z3, z5, z6, z7,
                                   hf, s2, Sbp, slot, rep);
}